// Round 1
// baseline (2915.852 us; speedup 1.0000x reference)
//
#include <hip/hip_runtime.h>
#include <hip/hip_bf16.h>
#include <math.h>

#define D_MODEL 1024
#define SEQ 2048
#define BATCH 2
#define NH 16
#define DH 64
#define D_HID 4096
#define MTOT (BATCH*SEQ)   // 4096 rows

// ---------------------------------------------------------------------------
// Tiled fp32 GEMM: C[M,N] = A[M,K] @ B[K,N] (+bias) (+gelu)
// 64x64 block tile, 256 threads, 4x4 micro-tile, K-step 16.
// EPI: 0 = none, 1 = +bias, 2 = +bias then exact GELU
// ---------------------------------------------------------------------------
#define BT 64
#define KS 16

__device__ __forceinline__ float gelu_exact(float x) {
    return 0.5f * x * (1.0f + erff(x * 0.70710678118654752f));
}

template <int EPI>
__global__ __launch_bounds__(256) void gemm_kernel(
    const float* __restrict__ A, const float* __restrict__ B,
    const float* __restrict__ bias, float* __restrict__ C,
    int M, int N, int K) {
    __shared__ float As[KS][BT + 4];
    __shared__ float Bs[KS][BT + 4];

    const int tid = threadIdx.x;
    const int tx = tid & 15;        // 0..15 -> col group
    const int ty = tid >> 4;        // 0..15 -> row group
    const int row0 = blockIdx.y * BT;
    const int col0 = blockIdx.x * BT;

    float acc[4][4] = {};

    for (int kk = 0; kk < K; kk += KS) {
        // Load A tile (64 rows x 16 k), transposed into As[k][row]
        {
            const int r  = tid >> 2;          // 0..63
            const int k4 = (tid & 3) * 4;     // 0,4,8,12
            const float4 v = *(const float4*)(A + (size_t)(row0 + r) * K + kk + k4);
            As[k4 + 0][r] = v.x;
            As[k4 + 1][r] = v.y;
            As[k4 + 2][r] = v.z;
            As[k4 + 3][r] = v.w;
        }
        // Load B tile (16 k x 64 cols)
        {
            const int kr = tid >> 4;          // 0..15
            const int c4 = (tid & 15) * 4;
            const float4 v = *(const float4*)(B + (size_t)(kk + kr) * N + col0 + c4);
            *(float4*)&Bs[kr][c4] = v;
        }
        __syncthreads();

        #pragma unroll
        for (int k = 0; k < KS; ++k) {
            const float4 a4 = *(const float4*)&As[k][ty * 4];
            const float4 b4 = *(const float4*)&Bs[k][tx * 4];
            const float a[4] = {a4.x, a4.y, a4.z, a4.w};
            const float b[4] = {b4.x, b4.y, b4.z, b4.w};
            #pragma unroll
            for (int i = 0; i < 4; ++i)
                #pragma unroll
                for (int j = 0; j < 4; ++j)
                    acc[i][j] += a[i] * b[j];
        }
        __syncthreads();
    }

    // Epilogue: bias / gelu, vectorized store
    #pragma unroll
    for (int i = 0; i < 4; ++i) {
        const int r = row0 + ty * 4 + i;
        const int c = col0 + tx * 4;
        float4 v = make_float4(acc[i][0], acc[i][1], acc[i][2], acc[i][3]);
        if (EPI >= 1) {
            const float4 bb = *(const float4*)(bias + c);
            v.x += bb.x; v.y += bb.y; v.z += bb.z; v.w += bb.w;
        }
        if (EPI == 2) {
            v.x = gelu_exact(v.x); v.y = gelu_exact(v.y);
            v.z = gelu_exact(v.z); v.w = gelu_exact(v.w);
        }
        *(float4*)(C + (size_t)r * N + c) = v;
    }
}

// ---------------------------------------------------------------------------
// Flash-style causal attention, fp32.
// grid: (S/QT, NH, BATCH), 256 threads.
// Thread t: q-row r = t>>3 (0..31), group cg = t&7 (8 threads per row).
// cg indexes both the 8-kcol slice (scores) and the 8-dim slice (output).
// ---------------------------------------------------------------------------
#define QT 32
#define KT 64

__global__ __launch_bounds__(256) void attn_kernel(
    const float* __restrict__ Qm, const float* __restrict__ Km,
    const float* __restrict__ Vm, float* __restrict__ Om) {
    __shared__ float Qs[QT][65];
    __shared__ float Ks[KT][65];
    __shared__ float Vs[KT][65];
    __shared__ float Ps[QT][65];

    const int tid = threadIdx.x;
    const int r  = tid >> 3;   // 0..31
    const int cg = tid & 7;    // 0..7
    const int b  = blockIdx.z;
    const int h  = blockIdx.y;
    const int q0 = blockIdx.x * QT;
    const size_t rs = NH * DH;  // 1024 row stride

    const float* Qbase = Qm + (size_t)b * SEQ * rs + (size_t)h * DH;
    const float* Kbase = Km + (size_t)b * SEQ * rs + (size_t)h * DH;
    const float* Vbase = Vm + (size_t)b * SEQ * rs + (size_t)h * DH;

    // Load Q tile (scaled by 1/sqrt(64)): 32x64 floats = 512 float4
    for (int e = tid; e < QT * 16; e += 256) {
        const int qr = e >> 4;
        const int d4 = (e & 15) * 4;
        float4 v = *(const float4*)(Qbase + (size_t)(q0 + qr) * rs + d4);
        Qs[qr][d4 + 0] = v.x * 0.125f;
        Qs[qr][d4 + 1] = v.y * 0.125f;
        Qs[qr][d4 + 2] = v.z * 0.125f;
        Qs[qr][d4 + 3] = v.w * 0.125f;
    }

    float m = -INFINITY, l = 0.f;
    float acc[8] = {0.f, 0.f, 0.f, 0.f, 0.f, 0.f, 0.f, 0.f};
    const int qg = q0 + r;
    const int ktmax = (q0 + QT - 1) >> 6;

    for (int kt = 0; kt <= ktmax; ++kt) {
        __syncthreads();   // previous iteration done with Ks/Vs/Ps
        // Load K,V tiles: 64x64 each -> 1024 float4 each, 4 per thread
        for (int e = tid; e < KT * 16; e += 256) {
            const int kr = e >> 4;
            const int d4 = (e & 15) * 4;
            const size_t off = (size_t)(kt * KT + kr) * rs + d4;
            *(float4*)&Ks[kr][d4] = *(const float4*)(Kbase + off);
            *(float4*)&Vs[kr][d4] = *(const float4*)(Vbase + off);
        }
        __syncthreads();

        // Scores: row r, kcols cg*8..cg*8+7
        float s[8] = {0.f, 0.f, 0.f, 0.f, 0.f, 0.f, 0.f, 0.f};
        for (int d = 0; d < 64; ++d) {
            const float qv = Qs[r][d];
            #pragma unroll
            for (int j = 0; j < 8; ++j) s[j] += qv * Ks[cg * 8 + j][d];
        }
        // Causal mask + local max
        float lm = -INFINITY;
        #pragma unroll
        for (int j = 0; j < 8; ++j) {
            const int kg = kt * KT + cg * 8 + j;
            if (kg > qg) s[j] = -INFINITY;
            lm = fmaxf(lm, s[j]);
        }
        // Reduce max across the 8 threads of this row
        #pragma unroll
        for (int off = 1; off < 8; off <<= 1)
            lm = fmaxf(lm, __shfl_xor(lm, off, 8));

        const float newm = fmaxf(m, lm);        // finite: first kcol of tile always valid
        const float scale = expf(m - newm);     // m=-inf on first tile -> 0
        float ls = 0.f;
        #pragma unroll
        for (int j = 0; j < 8; ++j) {
            const float p = expf(s[j] - newm);  // -inf -> 0
            ls += p;
            Ps[r][cg * 8 + j] = p;
        }
        #pragma unroll
        for (int off = 1; off < 8; off <<= 1)
            ls += __shfl_xor(ls, off, 8);
        l = l * scale + ls;
        m = newm;
        #pragma unroll
        for (int j = 0; j < 8; ++j) acc[j] *= scale;

        __syncthreads();   // make Ps visible (plays safe across scheduling)

        // PV: acc[dims cg*8..+7] += sum_kc P[r][kc] * V[kc][dim]
        for (int kc = 0; kc < 64; ++kc) {
            const float pv = Ps[r][kc];
            #pragma unroll
            for (int j = 0; j < 8; ++j) acc[j] += pv * Vs[kc][cg * 8 + j];
        }
    }

    const float inv = 1.f / l;
    float* Ob = Om + (size_t)(b * SEQ + qg) * rs + (size_t)h * DH + cg * 8;
    float4 o0 = make_float4(acc[0] * inv, acc[1] * inv, acc[2] * inv, acc[3] * inv);
    float4 o1 = make_float4(acc[4] * inv, acc[5] * inv, acc[6] * inv, acc[7] * inv);
    *(float4*)(Ob + 0) = o0;
    *(float4*)(Ob + 4) = o1;
}

// ---------------------------------------------------------------------------
// Fused residual + LayerNorm: out[row] = resid[row] + LN(y[row])*g + b
// One block (256 threads) per row of 1024.
// ---------------------------------------------------------------------------
__global__ __launch_bounds__(256) void ln_residual_kernel(
    const float* __restrict__ resid, const float* __restrict__ y,
    const float* __restrict__ g, const float* __restrict__ bta,
    float* __restrict__ out) {
    const int row = blockIdx.x;
    const int t4 = threadIdx.x * 4;
    const float4 v = *(const float4*)(y + (size_t)row * D_MODEL + t4);

    float s  = v.x + v.y + v.z + v.w;
    float s2 = v.x * v.x + v.y * v.y + v.z * v.z + v.w * v.w;
    #pragma unroll
    for (int off = 1; off < 64; off <<= 1) {
        s  += __shfl_xor(s, off, 64);
        s2 += __shfl_xor(s2, off, 64);
    }
    __shared__ float red[8];
    const int wave = threadIdx.x >> 6;
    if ((threadIdx.x & 63) == 0) { red[wave] = s; red[4 + wave] = s2; }
    __syncthreads();
    s  = red[0] + red[1] + red[2] + red[3];
    s2 = red[4] + red[5] + red[6] + red[7];

    const float mu  = s * (1.f / D_MODEL);
    const float var = s2 * (1.f / D_MODEL) - mu * mu;
    const float rstd = rsqrtf(var + 1e-5f);

    const float4 rr = *(const float4*)(resid + (size_t)row * D_MODEL + t4);
    const float4 gg = *(const float4*)(g + t4);
    const float4 bb = *(const float4*)(bta + t4);
    float4 o;
    o.x = rr.x + (v.x - mu) * rstd * gg.x + bb.x;
    o.y = rr.y + (v.y - mu) * rstd * gg.y + bb.y;
    o.z = rr.z + (v.z - mu) * rstd * gg.z + bb.z;
    o.w = rr.w + (v.w - mu) * rstd * gg.w + bb.w;
    *(float4*)(out + (size_t)row * D_MODEL + t4) = o;
}

// ---------------------------------------------------------------------------
extern "C" void kernel_launch(void* const* d_in, const int* in_sizes, int n_in,
                              void* d_out, int out_size, void* d_ws, size_t ws_size,
                              hipStream_t stream) {
    const float* x     = (const float*)d_in[0];
    const float* wq    = (const float*)d_in[1];
    const float* bq    = (const float*)d_in[2];
    const float* wk    = (const float*)d_in[3];
    const float* bk    = (const float*)d_in[4];
    const float* wv    = (const float*)d_in[5];
    const float* bv    = (const float*)d_in[6];
    const float* wo    = (const float*)d_in[7];
    const float* ln1_g = (const float*)d_in[8];
    const float* ln1_b = (const float*)d_in[9];
    const float* w1    = (const float*)d_in[10];
    const float* b1    = (const float*)d_in[11];
    const float* w2    = (const float*)d_in[12];
    const float* ln2_g = (const float*)d_in[13];
    const float* ln2_b = (const float*)d_in[14];
    float* out = (float*)d_out;

    float* ws = (float*)d_ws;
    const size_t SZ = (size_t)MTOT * D_MODEL;     // 4096*1024 = 4M floats
    float* Qb  = ws;            // [4096,1024]
    float* Kb  = ws + SZ;       // [4096,1024]
    float* Vb  = ws + 2 * SZ;   // [4096,1024]
    float* CTX = ws + 3 * SZ;   // [4096,1024]
    float* X1  = ws + 4 * SZ;   // [4096,1024]
    float* H   = ws + 5 * SZ;   // [4096,4096] (4*SZ floats)
    float* ATT = Qb;            // reuse (Q dead after attention)
    float* FFN = Kb;            // reuse (K dead after attention)

    const dim3 blk(256);
    const dim3 g1k(D_MODEL / BT, MTOT / BT);      // N=1024 grids: 16 x 64
    const dim3 g4k(D_HID / BT, MTOT / BT);        // N=4096 grids: 64 x 64

    // QKV projections
    gemm_kernel<1><<<g1k, blk, 0, stream>>>(x, wq, bq, Qb, MTOT, D_MODEL, D_MODEL);
    gemm_kernel<1><<<g1k, blk, 0, stream>>>(x, wk, bk, Kb, MTOT, D_MODEL, D_MODEL);
    gemm_kernel<1><<<g1k, blk, 0, stream>>>(x, wv, bv, Vb, MTOT, D_MODEL, D_MODEL);

    // Causal attention
    attn_kernel<<<dim3(SEQ / QT, NH, BATCH), blk, 0, stream>>>(Qb, Kb, Vb, CTX);

    // Output projection (no bias)
    gemm_kernel<0><<<g1k, blk, 0, stream>>>(CTX, wo, nullptr, ATT, MTOT, D_MODEL, D_MODEL);

    // x1 = x + LN(attn_out)
    ln_residual_kernel<<<dim3(MTOT), blk, 0, stream>>>(x, ATT, ln1_g, ln1_b, X1);

    // FFN
    gemm_kernel<2><<<g4k, blk, 0, stream>>>(X1, w1, b1, H, MTOT, D_HID, D_MODEL);
    gemm_kernel<0><<<g1k, blk, 0, stream>>>(H, w2, nullptr, FFN, MTOT, D_MODEL, D_HID);

    // out = x1 + LN(ffn_out)
    ln_residual_kernel<<<dim3(MTOT), blk, 0, stream>>>(X1, FFN, ln2_g, ln2_b, out);
}

// Round 2
// 528.961 us; speedup vs baseline: 5.5124x; 5.5124x over previous
//
#include <hip/hip_runtime.h>
#include <hip/hip_bf16.h>
#include <math.h>

#define D_MODEL 1024
#define SEQ 2048
#define BATCH 2
#define NH 16
#define DH 64
#define D_HID 4096
#define MTOT (BATCH*SEQ)   // 4096 rows

typedef __attribute__((ext_vector_type(8))) short bf16x8;
typedef __attribute__((ext_vector_type(4))) float f32x4;

__device__ __forceinline__ unsigned short f2bf(float f) {
    unsigned int u = __float_as_uint(f);
    u += 0x7FFF + ((u >> 16) & 1);     // round-to-nearest-even
    return (unsigned short)(u >> 16);
}

__device__ __forceinline__ float gelu_exact(float x) {
    return 0.5f * x * (1.0f + erff(x * 0.70710678118654752f));
}

// async global->LDS, 16 bytes per lane. LDS dest must be linear: base + lane*16.
__device__ __forceinline__ void gload16(const void* g, void* l) {
    __builtin_amdgcn_global_load_lds(
        (__attribute__((address_space(1))) void*)(g),
        (__attribute__((address_space(3))) void*)(l), 16, 0, 0);
}

// ---------------------------------------------------------------------------
// bf16 MFMA GEMM, m97 structure: 128x128 tile, BK=32, 4 waves (2x2 of 64x64),
// 16x16x32 MFMA, global_load_lds width 16, 2 barriers per K-step.
// A: bf16 [M][K] row-major.  Bt: bf16 [N][K] row-major (pre-transposed).
// EPI: 0 = plain fp32 out; 2 = bias+GELU -> bf16 row-major; 3 = bias -> QKV scatter bf16
// ---------------------------------------------------------------------------
template<int EPI>
__global__ __launch_bounds__(256) void gemm_bf16(
    const unsigned short* __restrict__ A,
    const unsigned short* __restrict__ Bt,
    const float* __restrict__ bias,
    float* __restrict__ Cf,
    unsigned short* __restrict__ Cb,
    unsigned short* __restrict__ Qo,
    unsigned short* __restrict__ Ko,
    unsigned short* __restrict__ Vo,
    int M, int N, int K)
{
    __shared__ unsigned short As[128 * 32];
    __shared__ unsigned short Bs[128 * 32];

    const int tid = threadIdx.x;
    const int l   = tid & 63;
    const int w   = tid >> 6;
    const int wr  = w >> 1, wc = w & 1;
    const int fr  = l & 15, fg = l >> 4;
    const size_t row0 = (size_t)blockIdx.y * 128;
    const size_t col0 = (size_t)blockIdx.x * 128;

    const int srow = tid >> 2;          // 0..63
    const int scol = (tid & 3) * 8;     // 0,8,16,24
    const unsigned short* ga0 = A  + (row0 + srow) * K + scol;
    const unsigned short* ga1 = A  + (row0 + srow + 64) * K + scol;
    const unsigned short* gb0 = Bt + (col0 + srow) * K + scol;
    const unsigned short* gb1 = Bt + (col0 + srow + 64) * K + scol;

    f32x4 acc[4][4] = {};

    for (int kk = 0; kk < K; kk += 32) {
        gload16(ga0 + kk, &As[(size_t)tid * 8]);
        gload16(ga1 + kk, &As[2048 + (size_t)tid * 8]);
        gload16(gb0 + kk, &Bs[(size_t)tid * 8]);
        gload16(gb1 + kk, &Bs[2048 + (size_t)tid * 8]);
        __syncthreads();   // compiler emits vmcnt(0) drain before barrier

        bf16x8 af[4], bfv[4];
        #pragma unroll
        for (int m = 0; m < 4; ++m)
            af[m] = *(const bf16x8*)&As[(wr * 64 + m * 16 + fr) * 32 + fg * 8];
        #pragma unroll
        for (int n = 0; n < 4; ++n)
            bfv[n] = *(const bf16x8*)&Bs[(wc * 64 + n * 16 + fr) * 32 + fg * 8];
        #pragma unroll
        for (int m = 0; m < 4; ++m)
            #pragma unroll
            for (int n = 0; n < 4; ++n)
                acc[m][n] = __builtin_amdgcn_mfma_f32_16x16x32_bf16(
                    af[m], bfv[n], acc[m][n], 0, 0, 0);
        __syncthreads();
    }

    // Epilogue. C/D layout: col = n*16 + (l&15), row = m*16 + (l>>4)*4 + j
    #pragma unroll
    for (int m = 0; m < 4; ++m) {
        #pragma unroll
        for (int n = 0; n < 4; ++n) {
            const int c = (int)col0 + wc * 64 + n * 16 + fr;
            const float badd = (EPI >= 2) ? bias[c] : 0.f;
            #pragma unroll
            for (int j = 0; j < 4; ++j) {
                const size_t r = row0 + wr * 64 + m * 16 + fg * 4 + j;
                float v = acc[m][n][j] + badd;
                if (EPI == 0) {
                    Cf[r * N + c] = v;
                } else if (EPI == 2) {
                    Cb[r * N + c] = f2bf(gelu_exact(v));
                } else {  // QKV scatter to [B*H][S][64]
                    const int which = c >> 10;
                    const int h = (c >> 6) & 15;
                    const int d = c & 63;
                    const size_t bb = r >> 11;
                    const size_t s  = r & 2047;
                    unsigned short* dst = (which == 0) ? Qo : (which == 1) ? Ko : Vo;
                    dst[((bb * NH + h) * SEQ + s) * 64 + d] = f2bf(v);
                }
            }
        }
    }
}

// ---------------------------------------------------------------------------
// MFMA flash attention (causal). Q pre-scaled by 1/8 at weight-pack time.
// Block: 64 Q-rows, 4 waves x 16 rows. K-tiles of 64 staged in LDS.
// Layouts: Ks[kc][d] (pad 72), Vt[d][kc] (pad 72), Ps per-wave [16][72].
// ---------------------------------------------------------------------------
__global__ __launch_bounds__(256) void attn_mfma(
    const unsigned short* __restrict__ Qh,   // [B*H][S][64] bf16
    const unsigned short* __restrict__ Kh,
    const unsigned short* __restrict__ Vh,
    unsigned short* __restrict__ Ctx)        // [B][S][H*64] bf16
{
    __shared__ unsigned short Ks[64][72];
    __shared__ unsigned short Vt[64][72];
    __shared__ unsigned short Ps[4][16][72];

    const int tid = threadIdx.x;
    const int l   = tid & 63;
    const int w   = tid >> 6;
    const int fr  = l & 15, fg = l >> 4;
    const int q0  = blockIdx.x * 64;
    const int h   = blockIdx.y;
    const int b   = blockIdx.z;
    const size_t bh = ((size_t)(b * NH + h)) * SEQ * 64;

    // Q A-fragments for this wave's 16 rows (rows q0+w*16 .. +15)
    const int qrow = q0 + w * 16 + fr;
    const bf16x8 qf0 = *(const bf16x8*)(Qh + bh + (size_t)qrow * 64 + fg * 8);
    const bf16x8 qf1 = *(const bf16x8*)(Qh + bh + (size_t)qrow * 64 + 32 + fg * 8);

    f32x4 o[4] = {};
    float mrow[4] = {-INFINITY, -INFINITY, -INFINITY, -INFINITY};
    float lrow[4] = {0.f, 0.f, 0.f, 0.f};

    const int skr = tid >> 2;          // 0..63 staging row
    const int sc0 = (tid & 3) * 16;    // 0,16,32,48 staging col base

    const int ktmax = q0 >> 6;
    for (int kt = 0; kt <= ktmax; ++kt) {
        __syncthreads();
        {   // stage K row-major, V transposed
            const unsigned short* ksrc = Kh + bh + (size_t)(kt * 64 + skr) * 64 + sc0;
            *(bf16x8*)&Ks[skr][sc0]     = *(const bf16x8*)ksrc;
            *(bf16x8*)&Ks[skr][sc0 + 8] = *(const bf16x8*)(ksrc + 8);
            const unsigned short* vsrc = Vh + bh + (size_t)(kt * 64 + skr) * 64 + sc0;
            const bf16x8 v0 = *(const bf16x8*)vsrc;
            const bf16x8 v1 = *(const bf16x8*)(vsrc + 8);
            #pragma unroll
            for (int j = 0; j < 8; ++j) {
                Vt[sc0 + j][skr]     = (unsigned short)v0[j];
                Vt[sc0 + 8 + j][skr] = (unsigned short)v1[j];
            }
        }
        __syncthreads();

        // S = Q K^T  (C-layout: row q = fg*4+j, col kc = n*16+fr)
        f32x4 sf[4];
        #pragma unroll
        for (int n = 0; n < 4; ++n) {
            const bf16x8 kf0 = *(const bf16x8*)&Ks[n * 16 + fr][fg * 8];
            const bf16x8 kf1 = *(const bf16x8*)&Ks[n * 16 + fr][32 + fg * 8];
            f32x4 s = {0.f, 0.f, 0.f, 0.f};
            s = __builtin_amdgcn_mfma_f32_16x16x32_bf16(qf0, kf0, s, 0, 0, 0);
            s = __builtin_amdgcn_mfma_f32_16x16x32_bf16(qf1, kf1, s, 0, 0, 0);
            sf[n] = s;
        }

        if (kt == ktmax) {  // diagonal tile: mask col > row
            #pragma unroll
            for (int n = 0; n < 4; ++n)
                #pragma unroll
                for (int j = 0; j < 4; ++j) {
                    const int colg = q0 + n * 16 + fr;
                    const int rowg = q0 + w * 16 + fg * 4 + j;
                    if (colg > rowg) sf[n][j] = -INFINITY;
                }
        }

        // online softmax (rows live in 16-lane groups sharing fg)
        float pm[4];
        #pragma unroll
        for (int j = 0; j < 4; ++j)
            pm[j] = fmaxf(fmaxf(sf[0][j], sf[1][j]), fmaxf(sf[2][j], sf[3][j]));
        #pragma unroll
        for (int j = 0; j < 4; ++j)
            #pragma unroll
            for (int off = 1; off < 16; off <<= 1)
                pm[j] = fmaxf(pm[j], __shfl_xor(pm[j], off, 64));

        float sc[4], ls[4];
        #pragma unroll
        for (int j = 0; j < 4; ++j) {
            const float mn = fmaxf(mrow[j], pm[j]);
            sc[j] = __expf(mrow[j] - mn);
            mrow[j] = mn;
            ls[j] = 0.f;
        }
        #pragma unroll
        for (int n = 0; n < 4; ++n)
            #pragma unroll
            for (int j = 0; j < 4; ++j) {
                const float p = __expf(sf[n][j] - mrow[j]);
                sf[n][j] = p;
                ls[j] += p;
            }
        #pragma unroll
        for (int j = 0; j < 4; ++j) {
            #pragma unroll
            for (int off = 1; off < 16; off <<= 1)
                ls[j] += __shfl_xor(ls[j], off, 64);
            lrow[j] = lrow[j] * sc[j] + ls[j];
        }
        #pragma unroll
        for (int n = 0; n < 4; ++n)
            #pragma unroll
            for (int j = 0; j < 4; ++j)
                o[n][j] *= sc[j];

        // P -> bf16 -> per-wave LDS (A-layout source: [row q][kc])
        #pragma unroll
        for (int n = 0; n < 4; ++n)
            #pragma unroll
            for (int j = 0; j < 4; ++j)
                Ps[w][fg * 4 + j][n * 16 + fr] = f2bf(sf[n][j]);

        // PV: O += P x V
        const bf16x8 pa0 = *(const bf16x8*)&Ps[w][fr][fg * 8];
        const bf16x8 pa1 = *(const bf16x8*)&Ps[w][fr][32 + fg * 8];
        #pragma unroll
        for (int n = 0; n < 4; ++n) {
            const bf16x8 vb0 = *(const bf16x8*)&Vt[n * 16 + fr][fg * 8];
            const bf16x8 vb1 = *(const bf16x8*)&Vt[n * 16 + fr][32 + fg * 8];
            o[n] = __builtin_amdgcn_mfma_f32_16x16x32_bf16(pa0, vb0, o[n], 0, 0, 0);
            o[n] = __builtin_amdgcn_mfma_f32_16x16x32_bf16(pa1, vb1, o[n], 0, 0, 0);
        }
    }

    // epilogue: normalize, write ctx bf16 [b][s][h*64+d]
    const size_t ob = (size_t)b * SEQ * D_MODEL + (size_t)h * 64;
    #pragma unroll
    for (int j = 0; j < 4; ++j) {
        const int rowg = q0 + w * 16 + fg * 4 + j;
        const float inv = 1.f / lrow[j];
        #pragma unroll
        for (int n = 0; n < 4; ++n)
            Ctx[ob + (size_t)rowg * D_MODEL + n * 16 + fr] = f2bf(o[n][j] * inv);
    }
}

// ---------------------------------------------------------------------------
// Fused residual + LayerNorm; optionally also emits bf16 copy for next GEMM.
// ---------------------------------------------------------------------------
template<bool WB>
__global__ __launch_bounds__(256) void ln_residual(
    const float* __restrict__ resid, const float* __restrict__ y,
    const float* __restrict__ g, const float* __restrict__ bta,
    float* __restrict__ outf, unsigned short* __restrict__ outb) {
    const int row = blockIdx.x;
    const int t4 = threadIdx.x * 4;
    const float4 v = *(const float4*)(y + (size_t)row * D_MODEL + t4);

    float s  = v.x + v.y + v.z + v.w;
    float s2 = v.x * v.x + v.y * v.y + v.z * v.z + v.w * v.w;
    #pragma unroll
    for (int off = 1; off < 64; off <<= 1) {
        s  += __shfl_xor(s, off, 64);
        s2 += __shfl_xor(s2, off, 64);
    }
    __shared__ float red[8];
    const int wave = threadIdx.x >> 6;
    if ((threadIdx.x & 63) == 0) { red[wave] = s; red[4 + wave] = s2; }
    __syncthreads();
    s  = red[0] + red[1] + red[2] + red[3];
    s2 = red[4] + red[5] + red[6] + red[7];

    const float mu  = s * (1.f / D_MODEL);
    const float var = s2 * (1.f / D_MODEL) - mu * mu;
    const float rstd = rsqrtf(var + 1e-5f);

    const float4 rr = *(const float4*)(resid + (size_t)row * D_MODEL + t4);
    const float4 gg = *(const float4*)(g + t4);
    const float4 bb = *(const float4*)(bta + t4);
    float4 o;
    o.x = rr.x + (v.x - mu) * rstd * gg.x + bb.x;
    o.y = rr.y + (v.y - mu) * rstd * gg.y + bb.y;
    o.z = rr.z + (v.z - mu) * rstd * gg.z + bb.z;
    o.w = rr.w + (v.w - mu) * rstd * gg.w + bb.w;
    *(float4*)(outf + (size_t)row * D_MODEL + t4) = o;
    if (WB) {
        uint2 pv;
        pv.x = (unsigned)f2bf(o.x) | ((unsigned)f2bf(o.y) << 16);
        pv.y = (unsigned)f2bf(o.z) | ((unsigned)f2bf(o.w) << 16);
        *(uint2*)(outb + (size_t)row * D_MODEL + t4) = pv;
    }
}

// ---------------------------------------------------------------------------
// Packing kernels (run every call; ~20 us total)
// ---------------------------------------------------------------------------
__global__ void pack_bf16(const float* __restrict__ in, unsigned short* __restrict__ out, int n) {
    const int i = (blockIdx.x * 256 + threadIdx.x) * 4;
    if (i + 3 >= n) { for (int k = i; k < n; ++k) out[k] = f2bf(in[k]); return; }
    const float4 v = *(const float4*)(in + i);
    uint2 pv;
    pv.x = (unsigned)f2bf(v.x) | ((unsigned)f2bf(v.y) << 16);
    pv.y = (unsigned)f2bf(v.z) | ((unsigned)f2bf(v.w) << 16);
    *(uint2*)(out + i) = pv;
}

__global__ void pack_bias(const float* __restrict__ bq, const float* __restrict__ bk,
                          const float* __restrict__ bv, float* __restrict__ outb) {
    const int i = blockIdx.x * 256 + threadIdx.x;   // 0..3071
    outb[i] = (i < 1024) ? bq[i] * 0.125f : (i < 2048) ? bk[i - 1024] : bv[i - 2048];
}

// W fp32 [K][N] -> Out bf16 [orow+N][K] (transposed), optional scale.
__global__ __launch_bounds__(256) void transpose_pack(
    const float* __restrict__ W, unsigned short* __restrict__ Out,
    int K, int N, float scale, int orow) {
    __shared__ float t[32][33];
    const int tx = threadIdx.x & 31, ty = threadIdx.x >> 5;  // ty 0..7
    const int k0 = blockIdx.y * 32, n0 = blockIdx.x * 32;
    #pragma unroll
    for (int i = 0; i < 4; ++i)
        t[ty + i * 8][tx] = W[(size_t)(k0 + ty + i * 8) * N + n0 + tx];
    __syncthreads();
    #pragma unroll
    for (int i = 0; i < 4; ++i) {
        const int n = ty + i * 8;
        Out[(size_t)(orow + n0 + n) * K + k0 + tx] = f2bf(t[tx][n] * scale);
    }
}

// ---------------------------------------------------------------------------
extern "C" void kernel_launch(void* const* d_in, const int* in_sizes, int n_in,
                              void* d_out, int out_size, void* d_ws, size_t ws_size,
                              hipStream_t stream) {
    const float* x     = (const float*)d_in[0];
    const float* wq    = (const float*)d_in[1];
    const float* bq    = (const float*)d_in[2];
    const float* wk    = (const float*)d_in[3];
    const float* bk    = (const float*)d_in[4];
    const float* wv    = (const float*)d_in[5];
    const float* bv    = (const float*)d_in[6];
    const float* wo    = (const float*)d_in[7];
    const float* ln1_g = (const float*)d_in[8];
    const float* ln1_b = (const float*)d_in[9];
    const float* w1    = (const float*)d_in[10];
    const float* b1    = (const float*)d_in[11];
    const float* w2    = (const float*)d_in[12];
    const float* ln2_g = (const float*)d_in[13];
    const float* ln2_b = (const float*)d_in[14];
    float* out = (float*)d_out;

    char* base = (char*)d_ws;
    const size_t MB = 1 << 20;
    unsigned short* xb    = (unsigned short*)(base + 0 * MB);     // 8 MB
    unsigned short* WqkvT = (unsigned short*)(base + 8 * MB);     // 6 MB
    unsigned short* WoT   = (unsigned short*)(base + 14 * MB);    // 2 MB
    unsigned short* W1T   = (unsigned short*)(base + 16 * MB);    // 8 MB
    unsigned short* W2T   = (unsigned short*)(base + 24 * MB);    // 8 MB
    float*          bqkv  = (float*)        (base + 32 * MB);     // 12 KB
    unsigned short* Qh    = (unsigned short*)(base + 33 * MB);    // 8 MB
    unsigned short* Kh    = (unsigned short*)(base + 41 * MB);    // 8 MB
    unsigned short* Vh    = (unsigned short*)(base + 49 * MB);    // 8 MB
    unsigned short* CTXb  = (unsigned short*)(base + 57 * MB);    // 8 MB
    float*          ATT   = (float*)        (base + 65 * MB);     // 16 MB
    float*          X1    = (float*)        (base + 81 * MB);     // 16 MB
    unsigned short* X1b   = (unsigned short*)(base + 97 * MB);    // 8 MB
    unsigned short* Hb    = (unsigned short*)(base + 105 * MB);   // 32 MB
    float*          FFN   = (float*)        (base + 65 * MB);     // reuse ATT

    const dim3 blk(256);

    // pack inputs/weights to bf16 (Q-scale folded into wq/bq)
    pack_bf16<<<4096, blk, 0, stream>>>(x, xb, MTOT * D_MODEL);
    pack_bias<<<12, blk, 0, stream>>>(bq, bk, bv, bqkv);
    transpose_pack<<<dim3(32, 32),  blk, 0, stream>>>(wq, WqkvT, 1024, 1024, 0.125f, 0);
    transpose_pack<<<dim3(32, 32),  blk, 0, stream>>>(wk, WqkvT, 1024, 1024, 1.f, 1024);
    transpose_pack<<<dim3(32, 32),  blk, 0, stream>>>(wv, WqkvT, 1024, 1024, 1.f, 2048);
    transpose_pack<<<dim3(32, 32),  blk, 0, stream>>>(wo, WoT,  1024, 1024, 1.f, 0);
    transpose_pack<<<dim3(128, 32), blk, 0, stream>>>(w1, W1T,  1024, 4096, 1.f, 0);
    transpose_pack<<<dim3(32, 128), blk, 0, stream>>>(w2, W2T,  4096, 1024, 1.f, 0);

    // fused QKV projection -> scattered [B*H][S][64] bf16
    gemm_bf16<3><<<dim3(24, 32), blk, 0, stream>>>(xb, WqkvT, bqkv, nullptr, nullptr,
                                                   Qh, Kh, Vh, MTOT, 3072, 1024);
    // causal MFMA flash attention -> ctx bf16 [B][S][1024]
    attn_mfma<<<dim3(SEQ / 64, NH, BATCH), blk, 0, stream>>>(Qh, Kh, Vh, CTXb);
    // output projection (fp32 out)
    gemm_bf16<0><<<dim3(8, 32), blk, 0, stream>>>(CTXb, WoT, nullptr, ATT, nullptr,
                                                  nullptr, nullptr, nullptr, MTOT, 1024, 1024);
    // x1 = x + LN(att)
    ln_residual<true><<<dim3(MTOT), blk, 0, stream>>>(x, ATT, ln1_g, ln1_b, X1, X1b);
    // FFN
    gemm_bf16<2><<<dim3(32, 32), blk, 0, stream>>>(X1b, W1T, b1, nullptr, Hb,
                                                   nullptr, nullptr, nullptr, MTOT, D_HID, 1024);
    gemm_bf16<0><<<dim3(8, 32), blk, 0, stream>>>(Hb, W2T, nullptr, FFN, nullptr,
                                                  nullptr, nullptr, nullptr, MTOT, D_MODEL, D_HID);
    // out = x1 + LN(ffn)
    ln_residual<false><<<dim3(MTOT), blk, 0, stream>>>(X1, FFN, ln2_g, ln2_b, out, nullptr);
}

// Round 4
// 471.020 us; speedup vs baseline: 6.1905x; 1.1230x over previous
//
#include <hip/hip_runtime.h>
#include <hip/hip_bf16.h>
#include <math.h>

#define D_MODEL 1024
#define SEQ 2048
#define BATCH 2
#define NH 16
#define DH 64
#define D_HID 4096
#define MTOT (BATCH*SEQ)   // 4096 rows

typedef __attribute__((ext_vector_type(8))) short bf16x8;
typedef __attribute__((ext_vector_type(4))) float f32x4;

__device__ __forceinline__ unsigned short f2bf(float f) {
    unsigned int u = __float_as_uint(f);
    u += 0x7FFF + ((u >> 16) & 1);     // round-to-nearest-even
    return (unsigned short)(u >> 16);
}

__device__ __forceinline__ float gelu_exact(float x) {
    return 0.5f * x * (1.0f + erff(x * 0.70710678118654752f));
}

// async global->LDS, 16 bytes per lane. LDS dest = wave-uniform base + lane*16.
__device__ __forceinline__ void gload16(const void* g, void* l) {
    __builtin_amdgcn_global_load_lds(
        (__attribute__((address_space(1))) void*)(g),
        (__attribute__((address_space(3))) void*)(l), 16, 0, 0);
}

// ---------------------------------------------------------------------------
// bf16 MFMA GEMM, m97 structure: BMx128 tile, BK=32, 4 waves (2x2), 16x16x32
// MFMA, global_load_lds width 16, 2 barriers per K-step, bijective XCD swizzle.
// A: bf16 [M][K] row-major.  Bt: bf16 [N][K] row-major (pre-transposed).
// EPI: 0 = fp32 out; 2 = bias+GELU -> bf16; 3 = bias -> Q,K scatter + V^T scatter
// ---------------------------------------------------------------------------
template<int EPI, int BM>
__global__ __launch_bounds__(256) void gemm_bf16(
    const unsigned short* __restrict__ A,
    const unsigned short* __restrict__ Bt,
    const float* __restrict__ bias,
    float* __restrict__ Cf,
    unsigned short* __restrict__ Cb,
    unsigned short* __restrict__ Qo,
    unsigned short* __restrict__ Ko,
    unsigned short* __restrict__ Vo,
    int N, int K, int nbx)
{
    constexpr int MF = BM / 32;                 // m-fragments per wave
    __shared__ unsigned short As[BM * 32];
    __shared__ unsigned short Bs[128 * 32];

    const int nwg = (int)gridDim.x;
    int bid = (int)blockIdx.x;
    bid = (bid & 7) * (nwg >> 3) + (bid >> 3);  // XCD-contiguous chunks (nwg%8==0)
    const int bx = bid % nbx;
    const int by = bid / nbx;

    const int tid = threadIdx.x;
    const int l   = tid & 63;
    const int w   = tid >> 6;
    const int wr  = w >> 1, wc = w & 1;
    const int fr  = l & 15, fg = l >> 4;
    const size_t row0 = (size_t)by * BM;
    const size_t col0 = (size_t)bx * 128;

    const int srow = tid >> 2;          // 0..63
    const int scol = (tid & 3) * 8;     // 0,8,16,24
    const unsigned short* ga0 = A  + (row0 + srow) * K + scol;
    const unsigned short* ga1 = A  + (row0 + srow + (BM == 128 ? 64 : 0)) * K + scol;
    const unsigned short* gb0 = Bt + (col0 + srow) * K + scol;
    const unsigned short* gb1 = Bt + (col0 + srow + 64) * K + scol;

    f32x4 acc[MF][4] = {};

    for (int kk = 0; kk < K; kk += 32) {
        gload16(ga0 + kk, &As[(size_t)tid * 8]);
        if (BM == 128) gload16(ga1 + kk, &As[2048 + (size_t)tid * 8]);
        gload16(gb0 + kk, &Bs[(size_t)tid * 8]);
        gload16(gb1 + kk, &Bs[2048 + (size_t)tid * 8]);
        __syncthreads();

        bf16x8 af[MF], bfv[4];
        #pragma unroll
        for (int m = 0; m < MF; ++m)
            af[m] = *(const bf16x8*)&As[(wr * (BM / 2) + m * 16 + fr) * 32 + fg * 8];
        #pragma unroll
        for (int n = 0; n < 4; ++n)
            bfv[n] = *(const bf16x8*)&Bs[(wc * 64 + n * 16 + fr) * 32 + fg * 8];
        #pragma unroll
        for (int m = 0; m < MF; ++m)
            #pragma unroll
            for (int n = 0; n < 4; ++n)
                acc[m][n] = __builtin_amdgcn_mfma_f32_16x16x32_bf16(
                    af[m], bfv[n], acc[m][n], 0, 0, 0);
        __syncthreads();
    }

    // Epilogue. C/D layout: col = n*16 + (l&15), row = m*16 + (l>>4)*4 + j
    #pragma unroll
    for (int m = 0; m < MF; ++m) {
        #pragma unroll
        for (int n = 0; n < 4; ++n) {
            const int c = (int)col0 + wc * 64 + n * 16 + fr;
            const float badd = (EPI >= 2) ? bias[c] : 0.f;
            #pragma unroll
            for (int j = 0; j < 4; ++j) {
                const size_t r = row0 + wr * (BM / 2) + m * 16 + fg * 4 + j;
                float v = acc[m][n][j] + badd;
                if (EPI == 0) {
                    Cf[r * N + c] = v;
                } else if (EPI == 2) {
                    Cb[r * N + c] = f2bf(gelu_exact(v));
                } else {  // QKV scatter: Q,K -> [B*H][S][64]; V -> [B*H][64][S]
                    const int which = c >> 10;
                    const int h = (c >> 6) & 15;
                    const int d = c & 63;
                    const size_t bb = r >> 11;
                    const size_t s  = r & 2047;
                    if (which == 2)
                        Vo[((bb * NH + h) * 64 + d) * SEQ + s] = f2bf(v);
                    else {
                        unsigned short* dst = (which == 0) ? Qo : Ko;
                        dst[((bb * NH + h) * SEQ + s) * 64 + d] = f2bf(v);
                    }
                }
            }
        }
    }
}

// ---------------------------------------------------------------------------
// MFMA flash attention (causal). Q pre-scaled by 1/8 at weight-pack time.
// Block: 64 Q-rows, 4 waves x 16 rows. K-tiles of 64.
// K from [B*H][S][64]; V pre-transposed in GLOBAL [B*H][64][S] so both stage
// into padded LDS rows with vectorized copies (no in-kernel transpose).
// T14: next tile's global->reg loads issued before compute; ds_write after
// the next barrier. Longest blocks launch first (reversed blockIdx).
// ---------------------------------------------------------------------------
__global__ __launch_bounds__(256) void attn_mfma(
    const unsigned short* __restrict__ Qh,   // [B*H][S][64] bf16
    const unsigned short* __restrict__ Kh,   // [B*H][S][64] bf16
    const unsigned short* __restrict__ VTh,  // [B*H][64][S] bf16
    unsigned short* __restrict__ Ctx)        // [B][S][H*64] bf16
{
    __shared__ unsigned short Ks[64][72];
    __shared__ unsigned short Vt[64][72];
    __shared__ unsigned short Ps[4][16][72];

    const int tid  = threadIdx.x;
    const int lane = tid & 63;
    const int w    = tid >> 6;
    const int fr   = lane & 15, fg = lane >> 4;
    const int q0   = ((int)gridDim.x - 1 - (int)blockIdx.x) * 64;
    const int h    = blockIdx.y;
    const int b    = blockIdx.z;
    const size_t bh64 = ((size_t)(b * NH + h)) * SEQ * 64;

    // Q A-fragments for this wave's 16 rows
    const int qrow = q0 + w * 16 + fr;
    const bf16x8 qf0 = *(const bf16x8*)(Qh + bh64 + (size_t)qrow * 64 + fg * 8);
    const bf16x8 qf1 = *(const bf16x8*)(Qh + bh64 + (size_t)qrow * 64 + 32 + fg * 8);

    f32x4 o[4] = {};
    float mrow[4] = {-INFINITY, -INFINITY, -INFINITY, -INFINITY};
    float lrow[4] = {0.f, 0.f, 0.f, 0.f};

    const int skr = tid >> 2;          // 0..63 staging row
    const int sc0 = (tid & 3) * 16;    // 0,16,32,48 staging col base
    const unsigned short* Kg = Kh  + bh64 + (size_t)skr * 64 + sc0;   // +kt*4096
    const unsigned short* Vg = VTh + bh64 + (size_t)skr * SEQ + sc0;  // +kt*64

    // prologue: tile 0 into registers
    bf16x8 kr0 = *(const bf16x8*)Kg;
    bf16x8 kr1 = *(const bf16x8*)(Kg + 8);
    bf16x8 vr0 = *(const bf16x8*)Vg;
    bf16x8 vr1 = *(const bf16x8*)(Vg + 8);

    const int ktmax = q0 >> 6;
    for (int kt = 0; kt <= ktmax; ++kt) {
        __syncthreads();   // all waves done reading previous tile's LDS
        *(bf16x8*)&Ks[skr][sc0]     = kr0;
        *(bf16x8*)&Ks[skr][sc0 + 8] = kr1;
        *(bf16x8*)&Vt[skr][sc0]     = vr0;
        *(bf16x8*)&Vt[skr][sc0 + 8] = vr1;
        __syncthreads();   // tile ready
        if (kt < ktmax) {  // T14: issue next tile loads; latency hides under compute
            const unsigned short* kn = Kg + (size_t)(kt + 1) * 4096;
            const unsigned short* vn = Vg + (size_t)(kt + 1) * 64;
            kr0 = *(const bf16x8*)kn;  kr1 = *(const bf16x8*)(kn + 8);
            vr0 = *(const bf16x8*)vn;  vr1 = *(const bf16x8*)(vn + 8);
        }

        // S = Q K^T  (C-layout: row q = fg*4+j, col kc = n*16+fr)
        f32x4 sf[4];
        __builtin_amdgcn_s_setprio(1);
        #pragma unroll
        for (int n = 0; n < 4; ++n) {
            const bf16x8 kf0 = *(const bf16x8*)&Ks[n * 16 + fr][fg * 8];
            const bf16x8 kf1 = *(const bf16x8*)&Ks[n * 16 + fr][32 + fg * 8];
            f32x4 s = {0.f, 0.f, 0.f, 0.f};
            s = __builtin_amdgcn_mfma_f32_16x16x32_bf16(qf0, kf0, s, 0, 0, 0);
            s = __builtin_amdgcn_mfma_f32_16x16x32_bf16(qf1, kf1, s, 0, 0, 0);
            sf[n] = s;
        }
        __builtin_amdgcn_s_setprio(0);

        if (kt == ktmax) {  // diagonal tile: mask col > row
            #pragma unroll
            for (int n = 0; n < 4; ++n)
                #pragma unroll
                for (int j = 0; j < 4; ++j) {
                    const int colg = q0 + n * 16 + fr;
                    const int rowg = q0 + w * 16 + fg * 4 + j;
                    if (colg > rowg) sf[n][j] = -INFINITY;
                }
        }

        // online softmax (rows live in 16-lane groups sharing fg)
        float pm[4];
        #pragma unroll
        for (int j = 0; j < 4; ++j)
            pm[j] = fmaxf(fmaxf(sf[0][j], sf[1][j]), fmaxf(sf[2][j], sf[3][j]));
        #pragma unroll
        for (int j = 0; j < 4; ++j)
            #pragma unroll
            for (int off = 1; off < 16; off <<= 1)
                pm[j] = fmaxf(pm[j], __shfl_xor(pm[j], off, 64));

        float sc[4], ls[4];
        #pragma unroll
        for (int j = 0; j < 4; ++j) {
            const float mn = fmaxf(mrow[j], pm[j]);
            sc[j] = __expf(mrow[j] - mn);
            mrow[j] = mn;
            ls[j] = 0.f;
        }
        #pragma unroll
        for (int n = 0; n < 4; ++n)
            #pragma unroll
            for (int j = 0; j < 4; ++j) {
                const float p = __expf(sf[n][j] - mrow[j]);
                sf[n][j] = p;
                ls[j] += p;
            }
        #pragma unroll
        for (int j = 0; j < 4; ++j) {
            #pragma unroll
            for (int off = 1; off < 16; off <<= 1)
                ls[j] += __shfl_xor(ls[j], off, 64);
            lrow[j] = lrow[j] * sc[j] + ls[j];
        }
        #pragma unroll
        for (int n = 0; n < 4; ++n)
            #pragma unroll
            for (int j = 0; j < 4; ++j)
                o[n][j] *= sc[j];

        // P -> bf16 -> per-wave LDS (A-layout source: [row q][kc])
        #pragma unroll
        for (int n = 0; n < 4; ++n)
            #pragma unroll
            for (int j = 0; j < 4; ++j)
                Ps[w][fg * 4 + j][n * 16 + fr] = f2bf(sf[n][j]);

        const bf16x8 pa0 = *(const bf16x8*)&Ps[w][fr][fg * 8];
        const bf16x8 pa1 = *(const bf16x8*)&Ps[w][fr][32 + fg * 8];

        // PV: O += P x V   (V^T rows are d, cols kc -> contiguous b128 reads)
        __builtin_amdgcn_s_setprio(1);
        #pragma unroll
        for (int n = 0; n < 4; ++n) {
            const bf16x8 vb0 = *(const bf16x8*)&Vt[n * 16 + fr][fg * 8];
            const bf16x8 vb1 = *(const bf16x8*)&Vt[n * 16 + fr][32 + fg * 8];
            o[n] = __builtin_amdgcn_mfma_f32_16x16x32_bf16(pa0, vb0, o[n], 0, 0, 0);
            o[n] = __builtin_amdgcn_mfma_f32_16x16x32_bf16(pa1, vb1, o[n], 0, 0, 0);
        }
        __builtin_amdgcn_s_setprio(0);
    }

    // epilogue: normalize, write ctx bf16 [b][s][h*64+d]
    const size_t ob = (size_t)b * SEQ * D_MODEL + (size_t)h * 64;
    #pragma unroll
    for (int j = 0; j < 4; ++j) {
        const int rowg = q0 + w * 16 + fg * 4 + j;
        const float inv = 1.f / lrow[j];
        #pragma unroll
        for (int n = 0; n < 4; ++n)
            Ctx[ob + (size_t)rowg * D_MODEL + n * 16 + fr] = f2bf(o[n][j] * inv);
    }
}

// ---------------------------------------------------------------------------
// Fused residual + LayerNorm; optionally also emits bf16 copy for next GEMM.
// ---------------------------------------------------------------------------
template<bool WB>
__global__ __launch_bounds__(256) void ln_residual(
    const float* __restrict__ resid, const float* __restrict__ y,
    const float* __restrict__ g, const float* __restrict__ bta,
    float* __restrict__ outf, unsigned short* __restrict__ outb) {
    const int row = blockIdx.x;
    const int t4 = threadIdx.x * 4;
    const float4 v = *(const float4*)(y + (size_t)row * D_MODEL + t4);

    float s  = v.x + v.y + v.z + v.w;
    float s2 = v.x * v.x + v.y * v.y + v.z * v.z + v.w * v.w;
    #pragma unroll
    for (int off = 1; off < 64; off <<= 1) {
        s  += __shfl_xor(s, off, 64);
        s2 += __shfl_xor(s2, off, 64);
    }
    __shared__ float red[8];
    const int wave = threadIdx.x >> 6;
    if ((threadIdx.x & 63) == 0) { red[wave] = s; red[4 + wave] = s2; }
    __syncthreads();
    s  = red[0] + red[1] + red[2] + red[3];
    s2 = red[4] + red[5] + red[6] + red[7];

    const float mu  = s * (1.f / D_MODEL);
    const float var = s2 * (1.f / D_MODEL) - mu * mu;
    const float rstd = rsqrtf(var + 1e-5f);

    const float4 rr = *(const float4*)(resid + (size_t)row * D_MODEL + t4);
    const float4 gg = *(const float4*)(g + t4);
    const float4 bb = *(const float4*)(bta + t4);
    float4 o;
    o.x = rr.x + (v.x - mu) * rstd * gg.x + bb.x;
    o.y = rr.y + (v.y - mu) * rstd * gg.y + bb.y;
    o.z = rr.z + (v.z - mu) * rstd * gg.z + bb.z;
    o.w = rr.w + (v.w - mu) * rstd * gg.w + bb.w;
    *(float4*)(outf + (size_t)row * D_MODEL + t4) = o;
    if (WB) {
        uint2 pv;
        pv.x = (unsigned)f2bf(o.x) | ((unsigned)f2bf(o.y) << 16);
        pv.y = (unsigned)f2bf(o.z) | ((unsigned)f2bf(o.w) << 16);
        *(uint2*)(outb + (size_t)row * D_MODEL + t4) = pv;
    }
}

// ---------------------------------------------------------------------------
// Packing kernels (run every call; ~20 us total)
// ---------------------------------------------------------------------------
__global__ void pack_bf16(const float* __restrict__ in, unsigned short* __restrict__ out, int n) {
    const int i = (blockIdx.x * 256 + threadIdx.x) * 4;
    if (i + 3 >= n) { for (int k = i; k < n; ++k) out[k] = f2bf(in[k]); return; }
    const float4 v = *(const float4*)(in + i);
    uint2 pv;
    pv.x = (unsigned)f2bf(v.x) | ((unsigned)f2bf(v.y) << 16);
    pv.y = (unsigned)f2bf(v.z) | ((unsigned)f2bf(v.w) << 16);
    *(uint2*)(out + i) = pv;
}

__global__ void pack_bias(const float* __restrict__ bq, const float* __restrict__ bk,
                          const float* __restrict__ bv, float* __restrict__ outb) {
    const int i = blockIdx.x * 256 + threadIdx.x;   // 0..3071
    outb[i] = (i < 1024) ? bq[i] * 0.125f : (i < 2048) ? bk[i - 1024] : bv[i - 2048];
}

// W fp32 [K][N] -> Out bf16 [orow+N][K] (transposed), optional scale.
__global__ __launch_bounds__(256) void transpose_pack(
    const float* __restrict__ W, unsigned short* __restrict__ Out,
    int K, int N, float scale, int orow) {
    __shared__ float t[32][33];
    const int tx = threadIdx.x & 31, ty = threadIdx.x >> 5;  // ty 0..7
    const int k0 = blockIdx.y * 32, n0 = blockIdx.x * 32;
    #pragma unroll
    for (int i = 0; i < 4; ++i)
        t[ty + i * 8][tx] = W[(size_t)(k0 + ty + i * 8) * N + n0 + tx];
    __syncthreads();
    #pragma unroll
    for (int i = 0; i < 4; ++i) {
        const int n = ty + i * 8;
        Out[(size_t)(orow + n0 + n) * K + k0 + tx] = f2bf(t[tx][n] * scale);
    }
}

// ---------------------------------------------------------------------------
extern "C" void kernel_launch(void* const* d_in, const int* in_sizes, int n_in,
                              void* d_out, int out_size, void* d_ws, size_t ws_size,
                              hipStream_t stream) {
    const float* x     = (const float*)d_in[0];
    const float* wq    = (const float*)d_in[1];
    const float* bq    = (const float*)d_in[2];
    const float* wk    = (const float*)d_in[3];
    const float* bk    = (const float*)d_in[4];
    const float* wv    = (const float*)d_in[5];
    const float* bv    = (const float*)d_in[6];
    const float* wo    = (const float*)d_in[7];
    const float* ln1_g = (const float*)d_in[8];
    const float* ln1_b = (const float*)d_in[9];
    const float* w1    = (const float*)d_in[10];
    const float* b1    = (const float*)d_in[11];
    const float* w2    = (const float*)d_in[12];
    const float* ln2_g = (const float*)d_in[13];
    const float* ln2_b = (const float*)d_in[14];
    float* out = (float*)d_out;

    char* base = (char*)d_ws;
    const size_t MB = 1 << 20;
    unsigned short* xb    = (unsigned short*)(base + 0 * MB);     // 8 MB
    unsigned short* WqkvT = (unsigned short*)(base + 8 * MB);     // 6 MB
    unsigned short* WoT   = (unsigned short*)(base + 14 * MB);    // 2 MB
    unsigned short* W1T   = (unsigned short*)(base + 16 * MB);    // 8 MB
    unsigned short* W2T   = (unsigned short*)(base + 24 * MB);    // 8 MB
    float*          bqkv  = (float*)        (base + 32 * MB);     // 12 KB
    unsigned short* Qh    = (unsigned short*)(base + 33 * MB);    // 8 MB
    unsigned short* Kh    = (unsigned short*)(base + 41 * MB);    // 8 MB
    unsigned short* VTh   = (unsigned short*)(base + 49 * MB);    // 8 MB [B*H][64][S]
    unsigned short* CTXb  = (unsigned short*)(base + 57 * MB);    // 8 MB
    float*          ATT   = (float*)        (base + 65 * MB);     // 16 MB
    float*          X1    = (float*)        (base + 81 * MB);     // 16 MB
    unsigned short* X1b   = (unsigned short*)(base + 97 * MB);    // 8 MB
    unsigned short* Hb    = (unsigned short*)(base + 105 * MB);   // 32 MB
    float*          FFN   = (float*)        (base + 65 * MB);     // reuse ATT

    const dim3 blk(256);

    // pack inputs/weights to bf16 (Q-scale folded into wq/bq)
    pack_bf16<<<4096, blk, 0, stream>>>(x, xb, MTOT * D_MODEL);
    pack_bias<<<12, blk, 0, stream>>>(bq, bk, bv, bqkv);
    transpose_pack<<<dim3(32, 32),  blk, 0, stream>>>(wq, WqkvT, 1024, 1024, 0.125f, 0);
    transpose_pack<<<dim3(32, 32),  blk, 0, stream>>>(wk, WqkvT, 1024, 1024, 1.f, 1024);
    transpose_pack<<<dim3(32, 32),  blk, 0, stream>>>(wv, WqkvT, 1024, 1024, 1.f, 2048);
    transpose_pack<<<dim3(32, 32),  blk, 0, stream>>>(wo, WoT,  1024, 1024, 1.f, 0);
    transpose_pack<<<dim3(128, 32), blk, 0, stream>>>(w1, W1T,  1024, 4096, 1.f, 0);
    transpose_pack<<<dim3(32, 128), blk, 0, stream>>>(w2, W2T,  4096, 1024, 1.f, 0);

    // fused QKV projection -> Q,K [B*H][S][64]; V^T [B*H][64][S]  (768 blocks)
    gemm_bf16<3, 128><<<dim3(768), blk, 0, stream>>>(xb, WqkvT, bqkv, nullptr, nullptr,
                                                     Qh, Kh, VTh, 3072, 1024, 24);
    // causal MFMA flash attention -> ctx bf16 [B][S][1024]
    attn_mfma<<<dim3(SEQ / 64, NH, BATCH), blk, 0, stream>>>(Qh, Kh, VTh, CTXb);
    // output projection (fp32 out)   (BM=64: 512 blocks, 2/CU)
    gemm_bf16<0, 64><<<dim3(512), blk, 0, stream>>>(CTXb, WoT, nullptr, ATT, nullptr,
                                                    nullptr, nullptr, nullptr, 1024, 1024, 8);
    // x1 = x + LN(att)
    ln_residual<true><<<dim3(MTOT), blk, 0, stream>>>(x, ATT, ln1_g, ln1_b, X1, X1b);
    // FFN
    gemm_bf16<2, 128><<<dim3(1024), blk, 0, stream>>>(X1b, W1T, b1, nullptr, Hb,
                                                      nullptr, nullptr, nullptr, 4096, 1024, 32);
    gemm_bf16<0, 64><<<dim3(512), blk, 0, stream>>>(Hb, W2T, nullptr, FFN, nullptr,
                                                    nullptr, nullptr, nullptr, 1024, 4096, 8);
    // out = x1 + LN(ffn)
    ln_residual<false><<<dim3(MTOT), blk, 0, stream>>>(X1, FFN, ln2_g, ln2_b, out, nullptr);
}

// Round 5
// 454.091 us; speedup vs baseline: 6.4213x; 1.0373x over previous
//
#include <hip/hip_runtime.h>
#include <hip/hip_bf16.h>
#include <math.h>

#define D_MODEL 1024
#define SEQ 2048
#define BATCH 2
#define NH 16
#define DH 64
#define D_HID 4096
#define MTOT (BATCH*SEQ)   // 4096 rows
#define LOG2E 1.4426950408889634f

typedef __attribute__((ext_vector_type(8))) short bf16x8;
typedef __attribute__((ext_vector_type(4))) float f32x4;

__device__ __forceinline__ unsigned short f2bf(float f) {
    unsigned int u = __float_as_uint(f);
    u += 0x7FFF + ((u >> 16) & 1);     // round-to-nearest-even
    return (unsigned short)(u >> 16);
}

__device__ __forceinline__ float gelu_exact(float x) {
    return 0.5f * x * (1.0f + erff(x * 0.70710678118654752f));
}

// async global->LDS, 16 bytes per lane. LDS dest = wave-uniform base + lane*16.
__device__ __forceinline__ void gload16(const void* g, void* l) {
    __builtin_amdgcn_global_load_lds(
        (__attribute__((address_space(1))) void*)(g),
        (__attribute__((address_space(3))) void*)(l), 16, 0, 0);
}

// ---------------------------------------------------------------------------
// bf16 MFMA GEMM: BMx128 tile, BK=64 (two 32-K panels per stage), 4 waves,
// 16x16x32 MFMA, global_load_lds width 16, ONE barrier-pair per 64 K.
// LDS layout: panel ks (k-half) = [ks][rows][32] shorts -> identical read
// pattern to the proven BK=32 structure (64B row stride, 2-way max).
// Staging: 1KB chunks; chunk ch covers rows (ch%PCH)*16..+15, cols (ch/PCH)*32..+31.
// A: bf16 [M][K] row-major.  Bt: bf16 [N][K] row-major (pre-transposed).
// EPI: 0 = fp32 out; 2 = bias+GELU -> bf16; 3 = bias -> Q,K scatter + V^T scatter
// ---------------------------------------------------------------------------
template<int EPI, int BM>
__global__ __launch_bounds__(256) void gemm_bf16(
    const unsigned short* __restrict__ A,
    const unsigned short* __restrict__ Bt,
    const float* __restrict__ bias,
    float* __restrict__ Cf,
    unsigned short* __restrict__ Cb,
    unsigned short* __restrict__ Qo,
    unsigned short* __restrict__ Ko,
    unsigned short* __restrict__ Vo,
    int N, int K, int nbx)
{
    constexpr int MF   = BM / 32;   // m-fragments per wave
    constexpr int NCHA = BM / 8;    // 1KB chunks in A tile
    constexpr int PCHA = BM / 16;   // chunks per A panel
    __shared__ unsigned short As[BM * 64];
    __shared__ unsigned short Bs[128 * 64];

    const int nwg = (int)gridDim.x;
    int bid = (int)blockIdx.x;
    bid = (bid & 7) * (nwg >> 3) + (bid >> 3);  // XCD-contiguous chunks (nwg%8==0)
    const int bx = bid % nbx;
    const int by = bid / nbx;

    const int tid = threadIdx.x;
    const int l   = tid & 63;
    const int w   = tid >> 6;
    const int wr  = w >> 1, wc = w & 1;
    const int fr  = l & 15, fg = l >> 4;
    const size_t row0 = (size_t)by * BM;
    const size_t col0 = (size_t)bx * 128;

    const int rsub = l >> 2;        // 0..15 row within 16-row chunk stripe
    const int csub = (l & 3) * 8;   // 0,8,16,24 col within 32-col panel

    f32x4 acc[MF][4] = {};

    for (int kk = 0; kk < K; kk += 64) {
        #pragma unroll
        for (int i = 0; i < NCHA / 4; ++i) {
            const int ch = i * 4 + w;
            const int p = ch / PCHA, j = ch % PCHA;
            gload16(A + (row0 + j * 16 + rsub) * K + kk + p * 32 + csub,
                    &As[ch * 512 + l * 8]);
        }
        #pragma unroll
        for (int i = 0; i < 4; ++i) {
            const int ch = i * 4 + w;
            const int p = ch >> 3, j = ch & 7;
            gload16(Bt + (col0 + j * 16 + rsub) * K + kk + p * 32 + csub,
                    &Bs[ch * 512 + l * 8]);
        }
        __syncthreads();

        #pragma unroll
        for (int ks = 0; ks < 2; ++ks) {
            bf16x8 af[MF], bfv[4];
            #pragma unroll
            for (int m = 0; m < MF; ++m)
                af[m] = *(const bf16x8*)&As[ks * BM * 32 + (wr * (BM / 2) + m * 16 + fr) * 32 + fg * 8];
            #pragma unroll
            for (int n = 0; n < 4; ++n)
                bfv[n] = *(const bf16x8*)&Bs[ks * 4096 + (wc * 64 + n * 16 + fr) * 32 + fg * 8];
            #pragma unroll
            for (int m = 0; m < MF; ++m)
                #pragma unroll
                for (int n = 0; n < 4; ++n)
                    acc[m][n] = __builtin_amdgcn_mfma_f32_16x16x32_bf16(
                        af[m], bfv[n], acc[m][n], 0, 0, 0);
        }
        __syncthreads();
    }

    // Epilogue. C/D layout: col = n*16 + (l&15), row = m*16 + (l>>4)*4 + j
    #pragma unroll
    for (int m = 0; m < MF; ++m) {
        #pragma unroll
        for (int n = 0; n < 4; ++n) {
            const int c = (int)col0 + wc * 64 + n * 16 + fr;
            const float badd = (EPI >= 2) ? bias[c] : 0.f;
            #pragma unroll
            for (int j = 0; j < 4; ++j) {
                const size_t r = row0 + wr * (BM / 2) + m * 16 + fg * 4 + j;
                float v = acc[m][n][j] + badd;
                if (EPI == 0) {
                    Cf[r * N + c] = v;
                } else if (EPI == 2) {
                    Cb[r * N + c] = f2bf(gelu_exact(v));
                } else {  // QKV scatter: Q,K -> [B*H][S][64]; V -> [B*H][64][S]
                    const int which = c >> 10;
                    const int h = (c >> 6) & 15;
                    const int d = c & 63;
                    const size_t bb = r >> 11;
                    const size_t s  = r & 2047;
                    if (which == 2)
                        Vo[((bb * NH + h) * 64 + d) * SEQ + s] = f2bf(v);
                    else {
                        unsigned short* dst = (which == 0) ? Qo : Ko;
                        dst[((bb * NH + h) * SEQ + s) * 64 + d] = f2bf(v);
                    }
                }
            }
        }
    }
}

// ---------------------------------------------------------------------------
// MFMA flash attention (causal), QBLK=128: 4 waves x 32 rows. K-tiles of 64.
// Q pre-scaled by log2(e)/8 (exp2-based softmax). V pre-transposed in global
// [B*H][64][S]. T14 prefetch (reg round-trip), T13 defer-max (THR=8, log2
// units), T5 setprio around MFMA clusters. Longest blocks launch first.
// ---------------------------------------------------------------------------
__global__ __launch_bounds__(256) void attn_mfma(
    const unsigned short* __restrict__ Qh,   // [B*H][S][64] bf16 (pre-scaled)
    const unsigned short* __restrict__ Kh,   // [B*H][S][64] bf16
    const unsigned short* __restrict__ VTh,  // [B*H][64][S] bf16
    unsigned short* __restrict__ Ctx)        // [B][S][H*64] bf16
{
    __shared__ unsigned short Ks[64][72];
    __shared__ unsigned short Vt[64][72];
    __shared__ unsigned short Ps[4][32][72];

    const int tid  = threadIdx.x;
    const int lane = tid & 63;
    const int w    = tid >> 6;
    const int fr   = lane & 15, fg = lane >> 4;
    const int q0   = ((int)gridDim.x - 1 - (int)blockIdx.x) * 128;
    const int h    = blockIdx.y;
    const int b    = blockIdx.z;
    const size_t bh64 = ((size_t)(b * NH + h)) * SEQ * 64;

    // Q A-fragments: wave rows q0 + w*32 + u*16 + fr
    bf16x8 qf[2][2];
    #pragma unroll
    for (int u = 0; u < 2; ++u) {
        const int qrow = q0 + w * 32 + u * 16 + fr;
        qf[u][0] = *(const bf16x8*)(Qh + bh64 + (size_t)qrow * 64 + fg * 8);
        qf[u][1] = *(const bf16x8*)(Qh + bh64 + (size_t)qrow * 64 + 32 + fg * 8);
    }

    f32x4 o[2][4] = {};
    float mrow[2][4], lrow[2][4];
    #pragma unroll
    for (int u = 0; u < 2; ++u)
        #pragma unroll
        for (int j = 0; j < 4; ++j) { mrow[u][j] = -INFINITY; lrow[u][j] = 0.f; }

    const int skr = tid >> 2;          // 0..63 staging row
    const int sc0 = (tid & 3) * 16;    // 0,16,32,48 staging col base
    const unsigned short* Kg = Kh  + bh64 + (size_t)skr * 64 + sc0;   // +kt*4096
    const unsigned short* Vg = VTh + bh64 + (size_t)skr * SEQ + sc0;  // +kt*64

    // prologue: tile 0 into registers
    bf16x8 kr0 = *(const bf16x8*)Kg;
    bf16x8 kr1 = *(const bf16x8*)(Kg + 8);
    bf16x8 vr0 = *(const bf16x8*)Vg;
    bf16x8 vr1 = *(const bf16x8*)(Vg + 8);

    const int kdiag = q0 >> 6;
    const int ktmax = kdiag + 1;
    for (int kt = 0; kt <= ktmax; ++kt) {
        __syncthreads();   // all waves done reading previous tile's LDS
        *(bf16x8*)&Ks[skr][sc0]     = kr0;
        *(bf16x8*)&Ks[skr][sc0 + 8] = kr1;
        *(bf16x8*)&Vt[skr][sc0]     = vr0;
        *(bf16x8*)&Vt[skr][sc0 + 8] = vr1;
        __syncthreads();   // tile ready
        if (kt < ktmax) {  // T14: next tile loads hide under compute
            const unsigned short* kn = Kg + (size_t)(kt + 1) * 4096;
            const unsigned short* vn = Vg + (size_t)(kt + 1) * 64;
            kr0 = *(const bf16x8*)kn;  kr1 = *(const bf16x8*)(kn + 8);
            vr0 = *(const bf16x8*)vn;  vr1 = *(const bf16x8*)(vn + 8);
        }

        // S = Q K^T  (C-layout: row q = u*16 + fg*4+j, col kc = n*16+fr)
        f32x4 sf[2][4];
        __builtin_amdgcn_s_setprio(1);
        #pragma unroll
        for (int n = 0; n < 4; ++n) {
            const bf16x8 kf0 = *(const bf16x8*)&Ks[n * 16 + fr][fg * 8];
            const bf16x8 kf1 = *(const bf16x8*)&Ks[n * 16 + fr][32 + fg * 8];
            #pragma unroll
            for (int u = 0; u < 2; ++u) {
                f32x4 s = {0.f, 0.f, 0.f, 0.f};
                s = __builtin_amdgcn_mfma_f32_16x16x32_bf16(qf[u][0], kf0, s, 0, 0, 0);
                s = __builtin_amdgcn_mfma_f32_16x16x32_bf16(qf[u][1], kf1, s, 0, 0, 0);
                sf[u][n] = s;
            }
        }
        __builtin_amdgcn_s_setprio(0);

        if (kt >= kdiag) {  // diagonal region: mask col > row
            #pragma unroll
            for (int u = 0; u < 2; ++u)
                #pragma unroll
                for (int n = 0; n < 4; ++n)
                    #pragma unroll
                    for (int j = 0; j < 4; ++j) {
                        const int colg = kt * 64 + n * 16 + fr;
                        const int rowg = q0 + w * 32 + u * 16 + fg * 4 + j;
                        if (colg > rowg) sf[u][n][j] = -INFINITY;
                    }
        }

        // per-row max of this tile (reduce across the 16 fr lanes)
        float pm[2][4];
        #pragma unroll
        for (int u = 0; u < 2; ++u)
            #pragma unroll
            for (int j = 0; j < 4; ++j) {
                float v = fmaxf(fmaxf(sf[u][0][j], sf[u][1][j]),
                                fmaxf(sf[u][2][j], sf[u][3][j]));
                #pragma unroll
                for (int off = 1; off < 16; off <<= 1)
                    v = fmaxf(v, __shfl_xor(v, off, 64));
                pm[u][j] = v;
            }

        // T13 defer-max: skip rescale when no row grew by more than THR (log2)
        int ok = 1;
        #pragma unroll
        for (int u = 0; u < 2; ++u)
            #pragma unroll
            for (int j = 0; j < 4; ++j)
                ok &= (pm[u][j] <= mrow[u][j] + 8.f) ? 1 : 0;
        if (!__all(ok)) {
            #pragma unroll
            for (int u = 0; u < 2; ++u)
                #pragma unroll
                for (int j = 0; j < 4; ++j) {
                    const float mn = fmaxf(mrow[u][j], pm[u][j]);
                    const float sc = exp2f(mrow[u][j] - mn);   // -inf -> 0
                    mrow[u][j] = mn;
                    lrow[u][j] *= sc;
                    #pragma unroll
                    for (int n = 0; n < 4; ++n)
                        o[u][n][j] *= sc;
                }
        }

        // P = exp2(S - m); accumulate l; write P -> per-wave LDS bf16
        #pragma unroll
        for (int u = 0; u < 2; ++u) {
            float ls[4] = {0.f, 0.f, 0.f, 0.f};
            #pragma unroll
            for (int n = 0; n < 4; ++n)
                #pragma unroll
                for (int j = 0; j < 4; ++j) {
                    const float p = exp2f(sf[u][n][j] - mrow[u][j]);
                    ls[j] += p;
                    Ps[w][u * 16 + fg * 4 + j][n * 16 + fr] = f2bf(p);
                }
            #pragma unroll
            for (int j = 0; j < 4; ++j) {
                #pragma unroll
                for (int off = 1; off < 16; off <<= 1)
                    ls[j] += __shfl_xor(ls[j], off, 64);
                lrow[u][j] += ls[j];
            }
        }

        const bf16x8 pa0[2] = { *(const bf16x8*)&Ps[w][fr][fg * 8],
                                *(const bf16x8*)&Ps[w][16 + fr][fg * 8] };
        const bf16x8 pa1[2] = { *(const bf16x8*)&Ps[w][fr][32 + fg * 8],
                                *(const bf16x8*)&Ps[w][16 + fr][32 + fg * 8] };

        // PV: O += P x V   (V^T rows are d -> contiguous b128 reads)
        __builtin_amdgcn_s_setprio(1);
        #pragma unroll
        for (int n = 0; n < 4; ++n) {
            const bf16x8 vb0 = *(const bf16x8*)&Vt[n * 16 + fr][fg * 8];
            const bf16x8 vb1 = *(const bf16x8*)&Vt[n * 16 + fr][32 + fg * 8];
            #pragma unroll
            for (int u = 0; u < 2; ++u) {
                o[u][n] = __builtin_amdgcn_mfma_f32_16x16x32_bf16(pa0[u], vb0, o[u][n], 0, 0, 0);
                o[u][n] = __builtin_amdgcn_mfma_f32_16x16x32_bf16(pa1[u], vb1, o[u][n], 0, 0, 0);
            }
        }
        __builtin_amdgcn_s_setprio(0);
    }

    // epilogue: normalize, write ctx bf16 [b][s][h*64+d]
    const size_t ob = (size_t)b * SEQ * D_MODEL + (size_t)h * 64;
    #pragma unroll
    for (int u = 0; u < 2; ++u)
        #pragma unroll
        for (int j = 0; j < 4; ++j) {
            const int rowg = q0 + w * 32 + u * 16 + fg * 4 + j;
            const float inv = 1.f / lrow[u][j];
            #pragma unroll
            for (int n = 0; n < 4; ++n)
                Ctx[ob + (size_t)rowg * D_MODEL + n * 16 + fr] = f2bf(o[u][n][j] * inv);
        }
}

// ---------------------------------------------------------------------------
// Fused residual + LayerNorm; optionally also emits bf16 copy for next GEMM.
// ---------------------------------------------------------------------------
template<bool WB>
__global__ __launch_bounds__(256) void ln_residual(
    const float* __restrict__ resid, const float* __restrict__ y,
    const float* __restrict__ g, const float* __restrict__ bta,
    float* __restrict__ outf, unsigned short* __restrict__ outb) {
    const int row = blockIdx.x;
    const int t4 = threadIdx.x * 4;
    const float4 v = *(const float4*)(y + (size_t)row * D_MODEL + t4);

    float s  = v.x + v.y + v.z + v.w;
    float s2 = v.x * v.x + v.y * v.y + v.z * v.z + v.w * v.w;
    #pragma unroll
    for (int off = 1; off < 64; off <<= 1) {
        s  += __shfl_xor(s, off, 64);
        s2 += __shfl_xor(s2, off, 64);
    }
    __shared__ float red[8];
    const int wave = threadIdx.x >> 6;
    if ((threadIdx.x & 63) == 0) { red[wave] = s; red[4 + wave] = s2; }
    __syncthreads();
    s  = red[0] + red[1] + red[2] + red[3];
    s2 = red[4] + red[5] + red[6] + red[7];

    const float mu  = s * (1.f / D_MODEL);
    const float var = s2 * (1.f / D_MODEL) - mu * mu;
    const float rstd = rsqrtf(var + 1e-5f);

    const float4 rr = *(const float4*)(resid + (size_t)row * D_MODEL + t4);
    const float4 gg = *(const float4*)(g + t4);
    const float4 bb = *(const float4*)(bta + t4);
    float4 o;
    o.x = rr.x + (v.x - mu) * rstd * gg.x + bb.x;
    o.y = rr.y + (v.y - mu) * rstd * gg.y + bb.y;
    o.z = rr.z + (v.z - mu) * rstd * gg.z + bb.z;
    o.w = rr.w + (v.w - mu) * rstd * gg.w + bb.w;
    *(float4*)(outf + (size_t)row * D_MODEL + t4) = o;
    if (WB) {
        uint2 pv;
        pv.x = (unsigned)f2bf(o.x) | ((unsigned)f2bf(o.y) << 16);
        pv.y = (unsigned)f2bf(o.z) | ((unsigned)f2bf(o.w) << 16);
        *(uint2*)(outb + (size_t)row * D_MODEL + t4) = pv;
    }
}

// ---------------------------------------------------------------------------
// Packing kernels
// ---------------------------------------------------------------------------
__global__ void pack_bf16(const float* __restrict__ in, unsigned short* __restrict__ out, int n) {
    const int i = (blockIdx.x * 256 + threadIdx.x) * 4;
    if (i + 3 >= n) { for (int k = i; k < n; ++k) out[k] = f2bf(in[k]); return; }
    const float4 v = *(const float4*)(in + i);
    uint2 pv;
    pv.x = (unsigned)f2bf(v.x) | ((unsigned)f2bf(v.y) << 16);
    pv.y = (unsigned)f2bf(v.z) | ((unsigned)f2bf(v.w) << 16);
    *(uint2*)(out + i) = pv;
}

__global__ void pack_bias(const float* __restrict__ bq, const float* __restrict__ bk,
                          const float* __restrict__ bv, float* __restrict__ outb) {
    const int i = blockIdx.x * 256 + threadIdx.x;   // 0..3071
    outb[i] = (i < 1024) ? bq[i] * (0.125f * LOG2E) : (i < 2048) ? bk[i - 1024] : bv[i - 2048];
}

// Four 1024x1024 fp32 [K][N] weights -> bf16 [N][K] transposed, fused launch.
__global__ __launch_bounds__(256) void transpose_pack4(
    const float* __restrict__ W0, const float* __restrict__ W1,
    const float* __restrict__ W2, const float* __restrict__ W3,
    unsigned short* __restrict__ Oqkv, unsigned short* __restrict__ Oo) {
    const int z = blockIdx.z;
    const float* W = (z == 0) ? W0 : (z == 1) ? W1 : (z == 2) ? W2 : W3;
    unsigned short* Out = (z == 3) ? Oo : (Oqkv + (size_t)z * 1024 * 1024);
    const float scale = (z == 0) ? 0.125f * LOG2E : 1.f;
    __shared__ float t[32][33];
    const int tx = threadIdx.x & 31, ty = threadIdx.x >> 5;  // ty 0..7
    const int k0 = blockIdx.y * 32, n0 = blockIdx.x * 32;
    #pragma unroll
    for (int i = 0; i < 4; ++i)
        t[ty + i * 8][tx] = W[(size_t)(k0 + ty + i * 8) * 1024 + n0 + tx];
    __syncthreads();
    #pragma unroll
    for (int i = 0; i < 4; ++i) {
        const int n = ty + i * 8;
        Out[(size_t)(n0 + n) * 1024 + k0 + tx] = f2bf(t[tx][n] * scale);
    }
}

// W fp32 [K][N] -> Out bf16 [N][K] (transposed).
__global__ __launch_bounds__(256) void transpose_pack(
    const float* __restrict__ W, unsigned short* __restrict__ Out, int K, int N) {
    __shared__ float t[32][33];
    const int tx = threadIdx.x & 31, ty = threadIdx.x >> 5;
    const int k0 = blockIdx.y * 32, n0 = blockIdx.x * 32;
    #pragma unroll
    for (int i = 0; i < 4; ++i)
        t[ty + i * 8][tx] = W[(size_t)(k0 + ty + i * 8) * N + n0 + tx];
    __syncthreads();
    #pragma unroll
    for (int i = 0; i < 4; ++i) {
        const int n = ty + i * 8;
        Out[(size_t)(n0 + n) * K + k0 + tx] = f2bf(t[tx][n]);
    }
}

// ---------------------------------------------------------------------------
extern "C" void kernel_launch(void* const* d_in, const int* in_sizes, int n_in,
                              void* d_out, int out_size, void* d_ws, size_t ws_size,
                              hipStream_t stream) {
    const float* x     = (const float*)d_in[0];
    const float* wq    = (const float*)d_in[1];
    const float* bq    = (const float*)d_in[2];
    const float* wk    = (const float*)d_in[3];
    const float* bk    = (const float*)d_in[4];
    const float* wv    = (const float*)d_in[5];
    const float* bv    = (const float*)d_in[6];
    const float* wo    = (const float*)d_in[7];
    const float* ln1_g = (const float*)d_in[8];
    const float* ln1_b = (const float*)d_in[9];
    const float* w1    = (const float*)d_in[10];
    const float* b1    = (const float*)d_in[11];
    const float* w2    = (const float*)d_in[12];
    const float* ln2_g = (const float*)d_in[13];
    const float* ln2_b = (const float*)d_in[14];
    float* out = (float*)d_out;

    char* base = (char*)d_ws;
    const size_t MB = 1 << 20;
    unsigned short* xb    = (unsigned short*)(base + 0 * MB);     // 8 MB
    unsigned short* WqkvT = (unsigned short*)(base + 8 * MB);     // 6 MB
    unsigned short* WoT   = (unsigned short*)(base + 14 * MB);    // 2 MB
    unsigned short* W1T   = (unsigned short*)(base + 16 * MB);    // 8 MB
    unsigned short* W2T   = (unsigned short*)(base + 24 * MB);    // 8 MB
    float*          bqkv  = (float*)        (base + 32 * MB);     // 12 KB
    unsigned short* Qh    = (unsigned short*)(base + 33 * MB);    // 8 MB
    unsigned short* Kh    = (unsigned short*)(base + 41 * MB);    // 8 MB
    unsigned short* VTh   = (unsigned short*)(base + 49 * MB);    // 8 MB [B*H][64][S]
    unsigned short* CTXb  = (unsigned short*)(base + 57 * MB);    // 8 MB
    float*          ATT   = (float*)        (base + 65 * MB);     // 16 MB
    float*          X1    = (float*)        (base + 81 * MB);     // 16 MB
    unsigned short* X1b   = (unsigned short*)(base + 97 * MB);    // 8 MB
    unsigned short* Hb    = (unsigned short*)(base + 105 * MB);   // 32 MB
    float*          FFN   = (float*)        (base + 65 * MB);     // reuse ATT

    const dim3 blk(256);

    // pack inputs/weights to bf16 (log2e*Q-scale folded into wq/bq)
    pack_bf16<<<4096, blk, 0, stream>>>(x, xb, MTOT * D_MODEL);
    pack_bias<<<12, blk, 0, stream>>>(bq, bk, bv, bqkv);
    transpose_pack4<<<dim3(32, 32, 4), blk, 0, stream>>>(wq, wk, wv, wo, WqkvT, WoT);
    transpose_pack<<<dim3(128, 32), blk, 0, stream>>>(w1, W1T, 1024, 4096);
    transpose_pack<<<dim3(32, 128), blk, 0, stream>>>(w2, W2T, 4096, 1024);

    // fused QKV projection -> Q,K [B*H][S][64]; V^T [B*H][64][S]  (768 blocks)
    gemm_bf16<3, 128><<<dim3(768), blk, 0, stream>>>(xb, WqkvT, bqkv, nullptr, nullptr,
                                                     Qh, Kh, VTh, 3072, 1024, 24);
    // causal MFMA flash attention (QBLK=128) -> ctx bf16 [B][S][1024]
    attn_mfma<<<dim3(SEQ / 128, NH, BATCH), blk, 0, stream>>>(Qh, Kh, VTh, CTXb);
    // output projection (fp32 out)   (BM=64: 512 blocks)
    gemm_bf16<0, 64><<<dim3(512), blk, 0, stream>>>(CTXb, WoT, nullptr, ATT, nullptr,
                                                    nullptr, nullptr, nullptr, 1024, 1024, 8);
    // x1 = x + LN(att)
    ln_residual<true><<<dim3(MTOT), blk, 0, stream>>>(x, ATT, ln1_g, ln1_b, X1, X1b);
    // FFN
    gemm_bf16<2, 128><<<dim3(1024), blk, 0, stream>>>(X1b, W1T, b1, nullptr, Hb,
                                                      nullptr, nullptr, nullptr, 4096, 1024, 32);
    gemm_bf16<0, 64><<<dim3(512), blk, 0, stream>>>(Hb, W2T, nullptr, FFN, nullptr,
                                                    nullptr, nullptr, nullptr, 1024, 4096, 8);
    // out = x1 + LN(ffn)
    ln_residual<false><<<dim3(MTOT), blk, 0, stream>>>(X1, FFN, ln2_g, ln2_b, out, nullptr);
}